// Round 7
// baseline (372.448 us; speedup 1.0000x reference)
//
#include <hip/hip_runtime.h>
#include <hip/hip_bf16.h>

// DynamicGATLayer on MI355X — R11: 2 i-tiles per wave (halves j-loop VMEM
// instruction count per output row), j-halved blocks + tiny k3 combine.
// B=2, N=2048, F=128, FE=8, H=4, C=64, HC=256.
//
// Simplifications (verified passing R1-R10):
//  - A * sigmoid(E.W_edge+b) == 0  <=>  A == 0, so E/W_edge/b_edge unread.
//  - |leaky(ss+sd)| <~ 6 -> exp without max-subtraction safe in fp32.
//  - ss/sd pre-scaled by log2(e).
//  - Adj==0 predicate precomputed in k1 as bitmask zT ([row][q512][lq][step]).
//
// R11 rationale: R8 (VALU/epilogue), R9 (footprint), R10 (spill/depth) all
// NULL with k2 pinned at ~75us (R5/R6 subtraction). The only quantity
// conserved across every null is the j-loop's total VMEM instruction count
// (~400K: 6 loads per wave-step serving 16 i-rows); ~110 cyc/instr implied =
// per-instruction VMEM-path wall (4-segment scattered hT loads). Fix: each
// wave now computes TWO 16-row i-tiles from ONE B-fragment load set
// (10 MFMA per step: 2x4 acc + 2 denom) -> VMEM instrs per row halved.
// Block = 32 i-rows x 1024 j (grid 256 = 2b x 64it x 2jh), 16 waves =
// 4h x 4jq(256j = 8 steps). In-block combine of 4 jq via 3 LDS rounds
// (32KB buf); k3 combines the 2 jh partials + bias/ELU/LayerNorm.

#define BB 2
#define NN 2048
#define FF 128
#define HH 4
#define CC 64
#define HC 256
#define TN 8      // node rows per block, K1
#define JB (NN / 8)   // 256 j-blocks of 8
#define LOG2E 1.4426950408889634f

typedef __attribute__((ext_vector_type(8))) short short8;
typedef __attribute__((ext_vector_type(4))) float f32x4;

__device__ __forceinline__ float wave_sum(float v) {
#pragma unroll
    for (int m = 32; m >= 1; m >>= 1) v += __shfl_xor(v, m, 64);
    return v;
}

__device__ __forceinline__ unsigned short bf16rne(float x) {
    unsigned u = __float_as_uint(x);
    return (unsigned short)((u + 0x7fffu + ((u >> 16) & 1u)) >> 16);
}

// ---------------- K1 (unchanged since R7) ----------------
__global__ __launch_bounds__(256) void k1_proj(
    const float* __restrict__ X, const float* __restrict__ Adj,
    const float* __restrict__ Wg,
    const float* __restrict__ a_src, const float* __restrict__ a_dst,
    unsigned short* __restrict__ hT, float* __restrict__ ssT,
    float* __restrict__ sdT, unsigned char* __restrict__ zT)
{
    const int blk = blockIdx.x;               // B*N/TN blocks
    const int b  = blk / (NN / TN);
    const int n0 = (blk % (NN / TN)) * TN;
    const int tid = threadIdx.x;
    const int h = tid >> 6, c = tid & 63;

    float hv[TN];
#pragma unroll
    for (int r = 0; r < TN; ++r) hv[r] = 0.f;

    const float* xp = X + (size_t)(b * NN + n0) * FF;   // block-uniform base

#pragma unroll 4
    for (int f4 = 0; f4 < FF / 4; ++f4) {
        const int f = f4 * 4;
        const float w0 = Wg[(h * FF + f + 0) * CC + c];
        const float w1 = Wg[(h * FF + f + 1) * CC + c];
        const float w2 = Wg[(h * FF + f + 2) * CC + c];
        const float w3 = Wg[(h * FF + f + 3) * CC + c];
#pragma unroll
        for (int r = 0; r < TN; ++r) {
            float4 x4 = *(const float4*)(xp + r * FF + f);   // wave-uniform -> s_load
            hv[r] = fmaf(x4.x, w0, hv[r]);
            hv[r] = fmaf(x4.y, w1, hv[r]);
            hv[r] = fmaf(x4.z, w2, hv[r]);
            hv[r] = fmaf(x4.w, w3, hv[r]);
        }
    }

    union { short8 v; unsigned short u[8]; } pk;
#pragma unroll
    for (int r = 0; r < TN; ++r) pk.u[r] = bf16rne(hv[r]);
    *(short8*)&hT[((((size_t)b * HH + h) * JB + (n0 >> 3)) * CC + c) * 8] = pk.v;

    const float as = a_src[tid];
    const float ad = a_dst[tid];
#pragma unroll
    for (int r = 0; r < TN; ++r) {
        const int n = n0 + r;
        float s1 = wave_sum(hv[r] * as);
        float s2 = wave_sum(hv[r] * ad);
        if (c == 0) {
            ssT[(b * HH + h) * NN + n] = s1 * LOG2E;
            sdT[(b * HH + h) * NN + n] = s2 * LOG2E;
        }
    }

    // ---- Adj zero-bitmask sweep: rows n0..n0+7, all 2048 j ----
    {
        const int r = tid >> 5;
        const int s = tid & 31;
        const size_t row = (size_t)(b * NN + n0 + r);
        const float* ap = Adj + row * NN + s * 64;
        unsigned char* zp = zT + (row << 8);
#pragma unroll
        for (int k = 0; k < 8; ++k) {
            float4 a0 = *(const float4*)(ap + k * 8);
            float4 a1 = *(const float4*)(ap + k * 8 + 4);
            unsigned m = 0u;
            m |= (a0.x == 0.f) ? 1u   : 0u;
            m |= (a0.y == 0.f) ? 2u   : 0u;
            m |= (a0.z == 0.f) ? 4u   : 0u;
            m |= (a0.w == 0.f) ? 8u   : 0u;
            m |= (a1.x == 0.f) ? 16u  : 0u;
            m |= (a1.y == 0.f) ? 32u  : 0u;
            m |= (a1.z == 0.f) ? 64u  : 0u;
            m |= (a1.w == 0.f) ? 128u : 0u;
            const int jb = s * 8 + k;
            const int jq = jb >> 6, rem = jb & 63;
            const int it = rem >> 2, lq = rem & 3;
            zp[jq * 64 + lq * 16 + it] = (unsigned char)m;
        }
    }
}

// ---------------- K2 ----------------
struct Stage {
    float4 sda, sdb;  // sd, 8 floats
    short8 bfr[4];    // hT B-frags
};

__device__ __forceinline__ void load_stage(
    Stage& s, const float* sdp, const unsigned short* hb, int it)
{
    const int js = it * 32;
    s.sda = *(const float4*)(sdp + js);
    s.sdb = *(const float4*)(sdp + js + 4);
    const unsigned short* hp = hb + it * 2048;   // 4 jb per step * 64c * 8
#pragma unroll
    for (int ni = 0; ni < 4; ++ni)
        s.bfr[ni] = *(const short8*)(hp + ni * 128);   // +256B imm offsets
}

__device__ __forceinline__ void consume2(
    const Stage& s, float ss0, float ss1, bool wz,
    unsigned mb0, unsigned mb1,
    f32x4* acc0, f32x4* acc1, f32x4& accS0, f32x4& accS1, short8 onesv)
{
    const float sd[8] = {s.sda.x, s.sda.y, s.sda.z, s.sda.w,
                         s.sdb.x, s.sdb.y, s.sdb.z, s.sdb.w};
    float p0[8], p1[8];
    __builtin_amdgcn_s_setprio(1);
#pragma unroll
    for (int t = 0; t < 8; ++t) {
        float x0 = ss0 + sd[t];
        x0 = fmaxf(x0, 0.2f * x0);
        p0[t] = __builtin_amdgcn_exp2f(x0);
        float x1 = ss1 + sd[t];
        x1 = fmaxf(x1, 0.2f * x1);
        p1[t] = __builtin_amdgcn_exp2f(x1);
    }
    if (wz) {                                    // wave-uniform, rare
        if (__any((mb0 | mb1) != 0u)) {
#pragma unroll
            for (int t = 0; t < 8; ++t) {
                if ((mb0 >> t) & 1u) p0[t] = 0.f;
                if ((mb1 >> t) & 1u) p1[t] = 0.f;
            }
        }
    }
    union { short8 v; __hip_bfloat162 h2[4]; } pk0, pk1;
#pragma unroll
    for (int t = 0; t < 4; ++t) {
        pk0.h2[t] = __float22bfloat162_rn(make_float2(p0[2 * t], p0[2 * t + 1]));
        pk1.h2[t] = __float22bfloat162_rn(make_float2(p1[2 * t], p1[2 * t + 1]));
    }
    accS0 = __builtin_amdgcn_mfma_f32_16x16x32_bf16(pk0.v, onesv, accS0, 0, 0, 0);
    accS1 = __builtin_amdgcn_mfma_f32_16x16x32_bf16(pk1.v, onesv, accS1, 0, 0, 0);
#pragma unroll
    for (int ni = 0; ni < 4; ++ni) {
        acc0[ni] = __builtin_amdgcn_mfma_f32_16x16x32_bf16(pk0.v, s.bfr[ni], acc0[ni], 0, 0, 0);
        acc1[ni] = __builtin_amdgcn_mfma_f32_16x16x32_bf16(pk1.v, s.bfr[ni], acc1[ni], 0, 0, 0);
    }
    __builtin_amdgcn_s_setprio(0);
}

__global__ __launch_bounds__(1024, 2) void k2_attn(
    const unsigned short* __restrict__ hT, const float* __restrict__ ssT,
    const float* __restrict__ sdT, const unsigned char* __restrict__ zT,
    float* __restrict__ Pacc, float* __restrict__ Pden)
{
    __shared__ float accs[HH][32][64];      // 32 KB combine buffer
    __shared__ float lsb[HH][32];           // 512 B

    const int blk = blockIdx.x;             // b*128 + itile*2 + jh
    const int b     = blk >> 7;
    const int itile = (blk >> 1) & 63;
    const int jh    = blk & 1;
    const int i0    = itile * 32;
    const int tid  = threadIdx.x;
    const int wave = tid >> 6;
    const int h  = wave & 3;
    const int jq = wave >> 2;               // 256-j sub-range of this j-half
    const int l  = tid & 63;
    const int lr = l & 15;
    const int lq = l >> 4;

    const int row0 = i0 + lr, row1 = i0 + 16 + lr;
    const float ss0 = ssT[(b * HH + h) * NN + row0];
    const float ss1 = ssT[(b * HH + h) * NN + row1];

    // 8 mask bytes per row for this lane's 8 steps.
    // zT layout [row][q512][lq][step16]; our 256-j range sits at
    // q512 = jh*2+(jq>>1), steps (jq&1)*8 .. +8.
    const size_t zoff = (size_t)((jh * 2 + (jq >> 1)) * 64 + lq * 16 + (jq & 1) * 8);
    const uint2 mz0 = *(const uint2*)(zT + (((size_t)(b * NN + row0)) << 8) + zoff);
    const uint2 mz1 = *(const uint2*)(zT + (((size_t)(b * NN + row1)) << 8) + zoff);
    const unsigned long long m0 = ((unsigned long long)mz0.y << 32) | mz0.x;
    const unsigned long long m1 = ((unsigned long long)mz1.y << 32) | mz1.x;
    const bool wz = __any((m0 | m1) != 0ull);

    short8 onesv;
#pragma unroll
    for (int i = 0; i < 8; ++i) onesv[i] = (short)0x3F80;  // bf16 1.0 splat

    f32x4 acc0[4], acc1[4];
#pragma unroll
    for (int ni = 0; ni < 4; ++ni) {
        acc0[ni] = (f32x4){0.f, 0.f, 0.f, 0.f};
        acc1[ni] = (f32x4){0.f, 0.f, 0.f, 0.f};
    }
    f32x4 accS0 = (f32x4){0.f, 0.f, 0.f, 0.f};
    f32x4 accS1 = (f32x4){0.f, 0.f, 0.f, 0.f};

    const float* sdp = sdT + (b * HH + h) * NN + jh * 1024 + jq * 256 + lq * 8;
    // hT[b][h][jb][c][8]; lane base jb = jh*128 + jq*32 + lq, c = lr
    const unsigned short* hb =
        hT + ((((size_t)b * HH + h) * JB + jh * 128 + jq * 32 + lq) * CC + lr) * 8;

    // 8 steps of 32 j; 2-stage rotation, distance-2 prefetch.
    Stage s0, s1;
    load_stage(s0, sdp, hb, 0);
    load_stage(s1, sdp, hb, 1);
#pragma unroll 1
    for (int it = 0; it < 8; it += 2) {
        const unsigned mb00 = (unsigned)(m0 >> (it * 8)) & 0xffu;
        const unsigned mb10 = (unsigned)(m1 >> (it * 8)) & 0xffu;
        const unsigned mb01 = (unsigned)(m0 >> (it * 8 + 8)) & 0xffu;
        const unsigned mb11 = (unsigned)(m1 >> (it * 8 + 8)) & 0xffu;
        consume2(s0, ss0, ss1, wz, mb00, mb10, acc0, acc1, accS0, accS1, onesv);
        if (it + 2 < 8) load_stage(s0, sdp, hb, it + 2);
        consume2(s1, ss0, ss1, wz, mb01, mb11, acc0, acc1, accS0, accS1, onesv);
        if (it + 3 < 8) load_stage(s1, sdp, hb, it + 3);
    }

    // ---- combine the 4 jq partials within the block: 3 LDS rounds ----
#pragma unroll 1
    for (int rnd = 1; rnd <= 3; ++rnd) {
        if (jq == rnd) {
#pragma unroll
            for (int ni = 0; ni < 4; ++ni)
#pragma unroll
                for (int r = 0; r < 4; ++r) {
                    accs[h][lq * 4 + r][ni * 16 + lr]      = acc0[ni][r];
                    accs[h][16 + lq * 4 + r][ni * 16 + lr] = acc1[ni][r];
                }
            if (lr == 0)
#pragma unroll
                for (int r = 0; r < 4; ++r) {
                    lsb[h][lq * 4 + r]      = accS0[r];
                    lsb[h][16 + lq * 4 + r] = accS1[r];
                }
        }
        __syncthreads();
        if (jq == 0) {
#pragma unroll
            for (int ni = 0; ni < 4; ++ni)
#pragma unroll
                for (int r = 0; r < 4; ++r) {
                    acc0[ni][r] += accs[h][lq * 4 + r][ni * 16 + lr];
                    acc1[ni][r] += accs[h][16 + lq * 4 + r][ni * 16 + lr];
                }
#pragma unroll
            for (int r = 0; r < 4; ++r) {
                accS0[r] += lsb[h][lq * 4 + r];        // broadcast read
                accS1[r] += lsb[h][16 + lq * 4 + r];
            }
        }
        __syncthreads();
    }

    // ---- jq0 stores the jh-partial: Pacc[jh][b][row][hc], Pden[jh][b][row][h]
    if (jq == 0) {
        float* pa = Pacc + ((size_t)(jh * BB + b) * NN + i0) * HC + h * 64 + lr;
#pragma unroll
        for (int ni = 0; ni < 4; ++ni)
#pragma unroll
            for (int r = 0; r < 4; ++r) {
                pa[(size_t)(lq * 4 + r) * HC + ni * 16]      = acc0[ni][r];
                pa[(size_t)(16 + lq * 4 + r) * HC + ni * 16] = acc1[ni][r];
            }
        if (lr == 0) {
            float* pd = Pden + ((size_t)(jh * BB + b) * NN + i0) * HH + h;
#pragma unroll
            for (int r = 0; r < 4; ++r) {
                pd[(lq * 4 + r) * HH]      = accS0[r];
                pd[(16 + lq * 4 + r) * HH] = accS1[r];
            }
        }
    }
}

// ---------------- K3: combine 2 jh + bias + ELU + LayerNorm ----------------
__global__ __launch_bounds__(256) void k3_norm(
    const float* __restrict__ Pacc, const float* __restrict__ Pden,
    const float* __restrict__ b_gat, const float* __restrict__ gamma,
    const float* __restrict__ beta, float* __restrict__ out)
{
    const int blk = blockIdx.x;             // B*(N/16)
    const int b  = blk >> 7;
    const int i0 = (blk & 127) << 4;
    const int tid = threadIdx.x;
    const int row = tid >> 4;               // 16 rows/block
    const int q   = tid & 15;               // 16 hc per thread
    const int i   = i0 + row;
    const int h   = q >> 2;

    float4 s[4];
#pragma unroll
    for (int k = 0; k < 4; ++k) s[k] = make_float4(0.f, 0.f, 0.f, 0.f);
    float d = 0.f;

#pragma unroll
    for (int jh = 0; jh < 2; ++jh) {
        const float* pa = Pacc + ((size_t)(jh * BB + b) * NN + i) * HC + q * 16;
#pragma unroll
        for (int k = 0; k < 4; ++k) {
            float4 v = *(const float4*)(pa + k * 4);
            s[k].x += v.x; s[k].y += v.y; s[k].z += v.z; s[k].w += v.w;
        }
        d += Pden[((size_t)(jh * BB + b) * NN + i) * HH + h];
    }

    const float invd = 1.f / d;
    float vv[16];
    float S1 = 0.f, S2 = 0.f;
#pragma unroll
    for (int k = 0; k < 4; ++k) {
        float4 bg = *(const float4*)(b_gat + q * 16 + k * 4);
        float e[4] = {s[k].x, s[k].y, s[k].z, s[k].w};
        float g[4] = {bg.x, bg.y, bg.z, bg.w};
#pragma unroll
        for (int t = 0; t < 4; ++t) {
            float v = e[t] * invd + g[t];
            v = (v > 0.f) ? v : (__expf(v) - 1.f);   // ELU
            vv[k * 4 + t] = v;
            S1 += v;
            S2 += v * v;
        }
    }
#pragma unroll
    for (int m = 1; m <= 8; m <<= 1) {
        S1 += __shfl_xor(S1, m, 64);
        S2 += __shfl_xor(S2, m, 64);
    }
    const float mu  = S1 * (1.f / HC);
    const float var = S2 * (1.f / HC) - mu * mu;
    const float inv = rsqrtf(var + 1e-3f);

    float* op = out + (size_t)(b * NN + i) * HC + q * 16;
#pragma unroll
    for (int k = 0; k < 4; ++k) {
        float4 gm = *(const float4*)(gamma + q * 16 + k * 4);
        float4 bm = *(const float4*)(beta  + q * 16 + k * 4);
        float4 o;
        o.x = (vv[k * 4 + 0] - mu) * inv * gm.x + bm.x;
        o.y = (vv[k * 4 + 1] - mu) * inv * gm.y + bm.y;
        o.z = (vv[k * 4 + 2] - mu) * inv * gm.z + bm.z;
        o.w = (vv[k * 4 + 3] - mu) * inv * gm.w + bm.w;
        *(float4*)(op + k * 4) = o;
    }
}

extern "C" void kernel_launch(void* const* d_in, const int* in_sizes, int n_in,
                              void* d_out, int out_size, void* d_ws, size_t ws_size,
                              hipStream_t stream)
{
    const float* X     = (const float*)d_in[0];
    const float* Adj   = (const float*)d_in[1];
    // d_in[2..4] = E, W_edge, b_edge: unused (see header).
    const float* Wg    = (const float*)d_in[5];
    const float* a_src = (const float*)d_in[6];
    const float* a_dst = (const float*)d_in[7];
    const float* b_gat = (const float*)d_in[8];
    const float* gam   = (const float*)d_in[9];
    const float* bet   = (const float*)d_in[10];
    float* out = (float*)d_out;

    const size_t hT_elems = (size_t)BB * HH * CC * NN;   // ushort
    const size_t ss_elems = (size_t)BB * HH * NN;        // float
    const size_t zT_bytes = (size_t)BB * NN * 256;       // 1 MB

    unsigned short* hT = (unsigned short*)d_ws;
    float* ssT = (float*)(hT + hT_elems);
    float* sdT = ssT + ss_elems;
    unsigned char* zT = (unsigned char*)(sdT + ss_elems);
    float* Pacc = (float*)(zT + zT_bytes);               // 2*2*2048*256 f = 8 MB
    float* Pden = Pacc + (size_t)2 * BB * NN * HC;       // 2*2*2048*4 f = 128 KB

    k1_proj<<<BB * NN / TN, 256, 0, stream>>>(X, Adj, Wg, a_src, a_dst, hT, ssT, sdT, zT);
    k2_attn<<<BB * (NN / 16), 1024, 0, stream>>>(hT, ssT, sdT, zT, Pacc, Pden);
    k3_norm<<<BB * (NN / 16), 256, 0, stream>>>(Pacc, Pden, b_gat, gam, bet, out);
}